// Round 3
// baseline (471.569 us; speedup 1.0000x reference)
//
#include <hip/hip_runtime.h>
#include <stdint.h>

#define NN 8192
#define DIM 128
#define ALPHA 0.2f
#define MTILE 32
#define BTHREADS 512   // 8 waves: waves split K 8-ways, barrier-free K loop

typedef float f32x16 __attribute__((ext_vector_type(16)));
typedef short bf16x8 __attribute__((ext_vector_type(8)));

__device__ __forceinline__ float b2f(uint32_t u){
  uint32_t x = u << 16;
  float f;
  __builtin_memcpy(&f, &x, 4);
  return f;
}
__device__ __forceinline__ uint16_t f2b(float f){
  uint32_t x;
  __builtin_memcpy(&x, &f, 4);
  x += 0x7FFFu + ((x >> 16) & 1u);
  return (uint16_t)(x >> 16);
}

// s1[i] = nodes[i,:] . a[0:128], s2[i] = nodes[i,:] . a[128:256]  (all fp32)
__global__ void s_kernel(const float* __restrict__ nodes,
                         const float* __restrict__ a,
                         float* __restrict__ s1, float* __restrict__ s2){
  int row  = blockIdx.x * 4 + (threadIdx.x >> 6);
  int lane = threadIdx.x & 63;
  float2 nv  = *(const float2*)(nodes + row * DIM + lane * 2);
  float2 a1v = *(const float2*)(a + lane * 2);
  float2 a2v = *(const float2*)(a + DIM + lane * 2);
  float p1 = nv.x * a1v.x + nv.y * a1v.y;
  float p2 = nv.x * a2v.x + nv.y * a2v.y;
  #pragma unroll
  for (int off = 32; off; off >>= 1){
    p1 += __shfl_down(p1, off);
    p2 += __shfl_down(p2, off);
  }
  if (lane == 0){ s1[row] = p1; s2[row] = p2; }
}

// nodesT[n][k] = bf16(nodes[k][n])   (fp32 in, bf16 transposed out)
__global__ void t_kernel(const float* __restrict__ nodes,
                         uint16_t* __restrict__ nodesT){
  __shared__ uint16_t tile[32][33];
  int kb = blockIdx.x * 32, nb = blockIdx.y * 32;
  int tx = threadIdx.x & 31, ty = threadIdx.x >> 5;  // ty in [0,8)
  for (int r = ty; r < 32; r += 8)
    tile[r][tx] = f2b(nodes[(size_t)(kb + r) * DIM + nb + tx]);
  __syncthreads();
  for (int r = ty; r < 32; r += 8)
    nodesT[(size_t)(nb + r) * NN + kb + tx] = tile[tx][r];
}

// Fused: W = mask * exp(leaky(s1+s2)); h' = (W @ nodes) / rowsum(W), fp32 out.
// One block per 32-row tile; 8 waves split K; LDS combine.
__global__ void __launch_bounds__(BTHREADS)
attn_kernel(const float* __restrict__ dist,
            const uint16_t* __restrict__ nodesT,
            const float* __restrict__ s1,
            const float* __restrict__ s2,
            float* __restrict__ out){
  const int tid  = threadIdx.x;
  const int wave = tid >> 6;    // 0..7
  const int lane = tid & 63;
  const int m    = lane & 31;   // A row / B-D column index
  const int half = lane >> 5;   // k-half within MFMA
  const int i0   = blockIdx.x * MTILE;

  const float s1v = s1[i0 + m];

  const int kwave = NN / (BTHREADS / 64);            // 1024 per wave
  const int kbeg  = wave * kwave;
  const int steps = kwave / 16;                      // 64

  f32x16 acc0, acc1, acc2, acc3;
  #pragma unroll
  for (int i = 0; i < 16; i++){ acc0[i] = 0.f; acc1[i] = 0.f; acc2[i] = 0.f; acc3[i] = 0.f; }
  float den = 0.f;

  const float*    dp  = dist   + (size_t)(i0 + m) * NN + kbeg + half * 8;
  const float*    sp  = s2     + kbeg + half * 8;
  const uint16_t* b0p = nodesT + (size_t)m * NN + kbeg + half * 8;
  const uint16_t* b1p = b0p + (size_t)32 * NN;
  const uint16_t* b2p = b0p + (size_t)64 * NN;
  const uint16_t* b3p = b0p + (size_t)96 * NN;

  for (int s = 0; s < steps; s++){
    float4 da  = *(const float4*)dp;
    float4 db  = *(const float4*)(dp + 4);
    float4 sa  = *(const float4*)sp;
    float4 sb  = *(const float4*)(sp + 4);
    uint4  nb0 = *(const uint4*)b0p;
    uint4  nb1 = *(const uint4*)b1p;
    uint4  nb2 = *(const uint4*)b2p;
    uint4  nb3 = *(const uint4*)b3p;

    float dv[8]  = {da.x, da.y, da.z, da.w, db.x, db.y, db.z, db.w};
    float s2v[8] = {sa.x, sa.y, sa.z, sa.w, sb.x, sb.y, sb.z, sb.w};

    union { bf16x8 v; uint16_t u[8]; } af;
    #pragma unroll
    for (int j = 0; j < 8; j++){
      float x = s1v + s2v[j];
      float e = fmaxf(x, ALPHA * x);
      float w = (dv[j] < 0.5f) ? __expf(e) : 0.f;
      uint16_t wq = f2b(w);
      af.u[j] = wq;
      den += b2f((uint32_t)wq);   // denominator from quantized weights
    }

    acc0 = __builtin_amdgcn_mfma_f32_32x32x16_bf16(af.v, *(const bf16x8*)&nb0, acc0, 0, 0, 0);
    acc1 = __builtin_amdgcn_mfma_f32_32x32x16_bf16(af.v, *(const bf16x8*)&nb1, acc1, 0, 0, 0);
    acc2 = __builtin_amdgcn_mfma_f32_32x32x16_bf16(af.v, *(const bf16x8*)&nb2, acc2, 0, 0, 0);
    acc3 = __builtin_amdgcn_mfma_f32_32x32x16_bf16(af.v, *(const bf16x8*)&nb3, acc3, 0, 0, 0);

    dp  += 16; sp  += 16;
    b0p += 16; b1p += 16; b2p += 16; b3p += 16;
  }

  // Combine 8 waves' partial tiles + denominators in LDS.
  __shared__ float accT[MTILE][DIM];
  __shared__ float denT[MTILE];
  for (int idx = tid; idx < MTILE * DIM; idx += BTHREADS) ((float*)accT)[idx] = 0.f;
  if (tid < MTILE) denT[tid] = 0.f;
  __syncthreads();

  #pragma unroll
  for (int r = 0; r < 16; r++){
    int row = (r & 3) + 8 * (r >> 2) + 4 * half;  // verified 32x32 C/D layout
    atomicAdd(&accT[row][ 0 + m], acc0[r]);
    atomicAdd(&accT[row][32 + m], acc1[r]);
    atomicAdd(&accT[row][64 + m], acc2[r]);
    atomicAdd(&accT[row][96 + m], acc3[r]);
  }
  atomicAdd(&denT[m], den);
  __syncthreads();

  if (tid < MTILE) denT[tid] = 1.0f / denT[tid];
  __syncthreads();

  for (int idx = tid; idx < MTILE * DIM; idx += BTHREADS){
    int row = idx >> 7, col = idx & 127;
    out[(size_t)(i0 + row) * DIM + col] = accT[row][col] * denT[row];
  }
}

extern "C" void kernel_launch(void* const* d_in, const int* in_sizes, int n_in,
                              void* d_out, int out_size, void* d_ws, size_t ws_size,
                              hipStream_t stream){
  const float* nodes = (const float*)d_in[0];
  const float* dist  = (const float*)d_in[1];
  const float* a     = (const float*)d_in[2];
  float* out = (float*)d_out;

  char* ws = (char*)d_ws;
  float*    s1     = (float*)ws;                     // 32 KB
  float*    s2     = (float*)(ws + (32 << 10));      // 32 KB
  uint16_t* nodesT = (uint16_t*)(ws + (64 << 10));   // 2 MB  -> total 2.06 MB

  s_kernel<<<NN / 4, 256, 0, stream>>>(nodes, a, s1, s2);
  t_kernel<<<dim3(NN / 32, DIM / 32), 256, 0, stream>>>(nodes, nodesT);
  attn_kernel<<<NN / MTILE, BTHREADS, 0, stream>>>(dist, nodesT, s1, s2, out);
}